// Round 12
// baseline (260.658 us; speedup 1.0000x reference)
//
#include <hip/hip_runtime.h>

// Problem dims
#define BB 8
#define LL 1024
#define DD 512
#define CC 4

typedef unsigned short u16;
typedef unsigned int u32;
typedef __attribute__((ext_vector_type(8))) short bf16x8;
typedef __attribute__((ext_vector_type(4))) float f32x4;
typedef __attribute__((ext_vector_type(4))) unsigned short u16x4;
typedef __attribute__((ext_vector_type(4))) float float4v;

typedef __attribute__((address_space(1))) const u32 gu32;
typedef __attribute__((address_space(3))) u32 lu32;
typedef __attribute__((address_space(3))) u16 l16;

__device__ __forceinline__ void gload16(const void* g, void* l) {
  __builtin_amdgcn_global_load_lds((gu32*)g, (lu32*)l, 16, 0, 0);
}
__device__ __forceinline__ u32 lds_off(const u16* p) {   // LDS byte offset
  return (u32)(uintptr_t)(l16*)p;
}

__device__ __forceinline__ u16 f2bf(float f) {
  unsigned u = __float_as_uint(f);
  u += 0x7FFF + ((u >> 16) & 1);   // round-to-nearest-even
  return (u16)(u >> 16);
}
__device__ __forceinline__ float bf2f(u16 h) {
  return __uint_as_float(((unsigned)h) << 16);
}
// saturation-safe fast tanh: 1 - 2/(e^{2x}+1)
__device__ __forceinline__ float fast_tanh(float x) {
  return 1.0f - 2.0f / (__expf(2.0f * x) + 1.0f);
}

// ---------------------------------------------------------------------------
// K0a: split fp32 X -> bf16 hi + bf16 lo
// ---------------------------------------------------------------------------
__global__ __launch_bounds__(256) void k_split(const float4v* __restrict__ x,
                                               u16* __restrict__ hi, u16* __restrict__ lo) {
  int i = blockIdx.x * 256 + threadIdx.x;
  float4v v = x[i];
  u16x4 h, l;
#pragma unroll
  for (int k = 0; k < 4; ++k) {
    u16 hh = f2bf(v[k]);
    h[k] = hh;
    l[k] = f2bf(v[k] - bf2f(hh));
  }
  *(u16x4*)&hi[(size_t)i * 4] = h;
  *(u16x4*)&lo[(size_t)i * 4] = l;
}

// ---------------------------------------------------------------------------
// K0b: transpose (C,D,D) weight and split to bf16 hi (+ optional lo)
// ---------------------------------------------------------------------------
__global__ __launch_bounds__(256) void k_tsplit(const float* __restrict__ w,
                                                u16* __restrict__ thi, u16* __restrict__ tlo) {
  __shared__ float t[32][33];
  int c = blockIdx.z;
  int tx = threadIdx.x;        // 0..31
  int ty = threadIdx.y;        // 0..7
  int e0 = blockIdx.x * 32, d0 = blockIdx.y * 32;
#pragma unroll
  for (int k = 0; k < 32; k += 8)
    t[ty + k][tx] = w[((size_t)c * DD + d0 + ty + k) * DD + e0 + tx];
  __syncthreads();
#pragma unroll
  for (int k = 0; k < 32; k += 8) {
    float v = t[tx][ty + k];
    size_t o = ((size_t)c * DD + e0 + ty + k) * DD + d0 + tx;
    u16 h = f2bf(v);
    thi[o] = h;
    if (tlo) tlo[o] = f2bf(v - bf2f(h));
  }
}

// ---------------------------------------------------------------------------
// 256x256-tile GEMM mainloop: C = A(MxK) · B(NxK)^T, row-major stride 512.
// 512 threads = 8 waves (wr 0..1, wc 0..3); wave tile 128x64 = 8x4 frags.
// BK=32, TRIPLE-buffered LDS [3][256][32] u16 per operand = 96 KB total.
// 16B-slot swizzle slot^=(row>>1)&3, source-side + read-side (0 conflicts).
// R12: staging issue SPREAD through the step (m196 fine-interleave):
//   iter t: STAGE_PAIR(t+2, half0) -> vmcnt(6) -> s_barrier ->
//           [ds_read/MFMA pipelined; STAGE_PAIR(t+2, half1) after cluster 2]
//           -> lgkm(0) -> s_barrier
// Ledger: at wait, outstanding = {t:4, t+1:4, t+2:2} = 10 -> vmcnt(6)
// retires exactly tile t's 4.  Peel waits 4 / 0 unchanged.
// SPLIT: 3 segments hi*hi + lo*hi + hi*lo (K-expanded 1536).
// ---------------------------------------------------------------------------
#define DSR(dst, addr, OFF) \
  asm volatile("ds_read_b128 %0, %1 offset:" #OFF : "=v"(dst) : "v"(addr))
#define LGKM(N) \
  do { __builtin_amdgcn_sched_barrier(0); \
       asm volatile("s_waitcnt lgkmcnt(" #N ")" ::: "memory"); \
       __builtin_amdgcn_sched_barrier(0); } while (0)

template<int NSEG, bool SPLIT>
__device__ __forceinline__ void gemm256(const u16* __restrict__ Ahi, const u16* __restrict__ Alo,
                                        const u16* __restrict__ Bhi, const u16* __restrict__ Blo,
                                        u16* lA, u16* lB, f32x4 (&acc)[8][4]) {
  const int tid = threadIdx.x;            // 0..511
  const int lane = tid & 63;
  const int wave = tid >> 6;              // 0..7
  const int wr = wave >> 2, wc = wave & 3;
  const int fr = lane & 15;
  const int fq = lane >> 4;               // quarter 0..3
  const int srow = tid >> 2;              // 0..127
  const int xs = (tid & 3) ^ ((srow >> 1) & 3);   // pre-swizzled source slot
  const size_t soff = (size_t)srow * DD + (size_t)xs * 8;
  const int sidx = fq ^ ((fr >> 1) & 3);
  const u32 ra = lds_off(lA) + (u32)((wr * 128 + fr) * 64 + sidx * 16);
  const u32 rb = lds_off(lB) + (u32)((wc * 64 + fr) * 64 + sidx * 16);

  const int NT = NSEG * 16;

  // one {A,B} pair for row-half `half` of tile t into buffer elem-offset beo
#define STAGE_PAIR(t, beo, half) do {                                         \
    const int seg_ = SPLIT ? ((t) >> 4) : 0;                                  \
    const int kp_ = ((t) & 15) * 32;                                          \
    const u16* As_ = (SPLIT && seg_ == 1) ? Alo : Ahi;                        \
    const u16* Bs_ = (SPLIT && seg_ == 2) ? Blo : Bhi;                        \
    gload16(As_ + soff + (size_t)(half) * 128 * DD + kp_,                     \
            lA + (beo) + tid * 8 + (half) * 4096);                            \
    gload16(Bs_ + soff + (size_t)(half) * 128 * DD + kp_,                     \
            lB + (beo) + tid * 8 + (half) * 4096);                            \
  } while (0)

#define MFMA2(m0, m1) do {                                                    \
    _Pragma("unroll")                                                         \
    for (int ni = 0; ni < 4; ++ni)                                            \
      acc[m0][ni] = __builtin_amdgcn_mfma_f32_16x16x32_bf16(                  \
          af[m0], bv[ni], acc[m0][ni], 0, 0, 0);                              \
    _Pragma("unroll")                                                         \
    for (int ni = 0; ni < 4; ++ni)                                            \
      acc[m1][ni] = __builtin_amdgcn_mfma_f32_16x16x32_bf16(                  \
          af[m1], bv[ni], acc[m1][ni], 0, 0, 0);                              \
  } while (0)

  // peel-version compute: no mid-issue
#define COMPUTE_PEEL(bo_) do {                                                \
    u32 aA_ = ra + (bo_), aB_ = rb + (bo_);                                   \
    bf16x8 af[8], bv[4];                                                      \
    DSR(bv[0], aB_, 0);    DSR(bv[1], aB_, 1024);                             \
    DSR(bv[2], aB_, 2048); DSR(bv[3], aB_, 3072);                             \
    DSR(af[0], aA_, 0);    DSR(af[1], aA_, 1024);                             \
    DSR(af[2], aA_, 2048); DSR(af[3], aA_, 3072);                             \
    LGKM(2);                                                                  \
    __builtin_amdgcn_s_setprio(1);                                            \
    MFMA2(0, 1);                                                              \
    DSR(af[4], aA_, 4096); DSR(af[5], aA_, 5120);                             \
    LGKM(2);                                                                  \
    MFMA2(2, 3);                                                              \
    DSR(af[6], aA_, 6144); DSR(af[7], aA_, 7168);                             \
    LGKM(2);                                                                  \
    MFMA2(4, 5);                                                              \
    LGKM(0);                                                                  \
    MFMA2(6, 7);                                                              \
    __builtin_amdgcn_s_setprio(0);                                            \
    __builtin_amdgcn_s_barrier();  /* reads retired: buf reusable */          \
  } while (0)

  STAGE_PAIR(0, 0, 0);      STAGE_PAIR(0, 0, 1);
  STAGE_PAIR(1, 8192, 0);   STAGE_PAIR(1, 8192, 1);
  int be = 16384;   // dest elems for stage t+2 at t=0 (buf 2)
  u32 bo = 0;       // read bytes for compute t at t=0 (buf 0)
#pragma unroll 1
  for (int t = 0; t < NT - 2; ++t) {
    STAGE_PAIR(t + 2, be, 0);
    __builtin_amdgcn_sched_barrier(0);
    asm volatile("s_waitcnt vmcnt(6)" ::: "memory");   // tile t landed
    __builtin_amdgcn_sched_barrier(0);
    __builtin_amdgcn_s_barrier();                      // data ready
    __builtin_amdgcn_sched_barrier(0);
    {
      u32 aA_ = ra + bo, aB_ = rb + bo;
      bf16x8 af[8], bv[4];
      DSR(bv[0], aB_, 0);    DSR(bv[1], aB_, 1024);
      DSR(bv[2], aB_, 2048); DSR(bv[3], aB_, 3072);
      DSR(af[0], aA_, 0);    DSR(af[1], aA_, 1024);
      DSR(af[2], aA_, 2048); DSR(af[3], aA_, 3072);
      LGKM(2);                    // bv0-3, af0-1 ready; af2-3 in flight
      __builtin_amdgcn_s_setprio(1);
      MFMA2(0, 1);
      DSR(af[4], aA_, 4096); DSR(af[5], aA_, 5120);
      LGKM(2);                    // af2-3 ready; af4-5 in flight
      MFMA2(2, 3);
      STAGE_PAIR(t + 2, be, 1);   // mid-step staging issue (fine interleave)
      DSR(af[6], aA_, 6144); DSR(af[7], aA_, 7168);
      LGKM(2);                    // af4-5 ready; af6-7 in flight
      MFMA2(4, 5);
      LGKM(0);                    // all reads retired
      MFMA2(6, 7);
      __builtin_amdgcn_s_setprio(0);
      __builtin_amdgcn_s_barrier();  // reads retired: buf reusable
    }
    be = (be == 16384) ? 0 : be + 8192;
    bo = (bo == 32768u) ? 0u : bo + 16384u;
  }
  // peel NT-2
  __builtin_amdgcn_sched_barrier(0);
  asm volatile("s_waitcnt vmcnt(4)" ::: "memory");
  __builtin_amdgcn_sched_barrier(0);
  __builtin_amdgcn_s_barrier();
  __builtin_amdgcn_sched_barrier(0);
  COMPUTE_PEEL(bo);
  bo = (bo == 32768u) ? 0u : bo + 16384u;
  // peel NT-1
  __builtin_amdgcn_sched_barrier(0);
  asm volatile("s_waitcnt vmcnt(0)" ::: "memory");
  __builtin_amdgcn_sched_barrier(0);
  __builtin_amdgcn_s_barrier();
  __builtin_amdgcn_sched_barrier(0);
  COMPUTE_PEEL(bo);
#undef STAGE_PAIR
#undef COMPUTE_PEEL
#undef MFMA2
}

// ---------------------------------------------------------------------------
// K1: mat_l[b,c] = X_b @ W_c  (split x split), epilogue splits result to bf16 hi/lo
// grid: 256 blocks (tm 0..3, tn 0..1 per bc), XCD-chunked decode
// ---------------------------------------------------------------------------
__global__ __launch_bounds__(512, 2) void k_matl(const u16* __restrict__ Xhi, const u16* __restrict__ Xlo,
                                                 const u16* __restrict__ Whi, const u16* __restrict__ Wlo,
                                                 u16* __restrict__ mhi, u16* __restrict__ mlo) {
  __shared__ u16 lA[3 * 256 * 32];
  __shared__ u16 lB[3 * 256 * 32];
  int lin = blockIdx.x;                       // 256
  int virt = (lin & 7) * 32 + (lin >> 3);     // XCD-chunked
  int bc = virt >> 3, rem = virt & 7;
  int tm = rem >> 1, tn = rem & 1;
  int b = bc >> 2, c = bc & 3;
  const u16* Ahi = Xhi + (size_t)b * LL * DD + (size_t)tm * 256 * DD;
  const u16* Alo = Xlo + (size_t)b * LL * DD + (size_t)tm * 256 * DD;
  const u16* Bhi = Whi + (size_t)c * DD * DD + (size_t)tn * 256 * DD;
  const u16* Blo = Wlo + (size_t)c * DD * DD + (size_t)tn * 256 * DD;
  f32x4 acc[8][4];
#pragma unroll
  for (int mi = 0; mi < 8; ++mi)
#pragma unroll
    for (int ni = 0; ni < 4; ++ni) acc[mi][ni] = (f32x4){0.f, 0.f, 0.f, 0.f};
  gemm256<3, true>(Ahi, Alo, Bhi, Blo, lA, lB, acc);

  int lane = threadIdx.x & 63, wave = threadIdx.x >> 6;
  int wr = wave >> 2, wc = wave & 3;
  int rgrp = (lane >> 4) * 4, cidx = lane & 15;
#pragma unroll
  for (int mi = 0; mi < 8; ++mi)
#pragma unroll
    for (int ni = 0; ni < 4; ++ni) {
      int row = tm * 256 + wr * 128 + mi * 16 + rgrp;
      int col = tn * 256 + wc * 64 + ni * 16 + cidx;
#pragma unroll
      for (int j = 0; j < 4; ++j) {
        float v = acc[mi][ni][j];
        size_t o = ((size_t)bc * LL + row + j) * DD + col;
        u16 h = f2bf(v);
        mhi[o] = h;
        mlo[o] = f2bf(v - bf2f(h));
      }
    }
}

// ---------------------------------------------------------------------------
// K2: s partials: per 256x256 tile of M = X_b @ mat_l[b,c]^T, tanh + row-sum
// grid: 512 blocks, XCD-chunked; s_part [bc][16][1024], slot = tn*4+wc
// ---------------------------------------------------------------------------
__global__ __launch_bounds__(512, 2) void k_s(const u16* __restrict__ Xhi, const u16* __restrict__ Xlo,
                                              const u16* __restrict__ mhi, const u16* __restrict__ mlo,
                                              const float* __restrict__ b_l, float* __restrict__ s_part) {
  __shared__ u16 lA[3 * 256 * 32];
  __shared__ u16 lB[3 * 256 * 32];
  int lin = blockIdx.x;                       // 512
  int virt = (lin & 7) * 64 + (lin >> 3);     // XCD-chunked
  int bc = virt >> 4, rem = virt & 15;
  int tm = rem >> 2, tn = rem & 3;
  int b = bc >> 2, c = bc & 3;
  const u16* Ahi = Xhi + (size_t)b * LL * DD + (size_t)tm * 256 * DD;
  const u16* Alo = Xlo + (size_t)b * LL * DD + (size_t)tm * 256 * DD;
  const u16* Bhi = mhi + (size_t)bc * LL * DD + (size_t)tn * 256 * DD;
  const u16* Blo = mlo + (size_t)bc * LL * DD + (size_t)tn * 256 * DD;
  f32x4 acc[8][4];
#pragma unroll
  for (int mi = 0; mi < 8; ++mi)
#pragma unroll
    for (int ni = 0; ni < 4; ++ni) acc[mi][ni] = (f32x4){0.f, 0.f, 0.f, 0.f};
  gemm256<3, true>(Ahi, Alo, Bhi, Blo, lA, lB, acc);

  int lane = threadIdx.x & 63, wave = threadIdx.x >> 6;
  int wr = wave >> 2, wc = wave & 3;
  float bl = b_l[c];
  float part[8][4];
#pragma unroll
  for (int mi = 0; mi < 8; ++mi)
#pragma unroll
    for (int j = 0; j < 4; ++j) part[mi][j] = 0.f;
#pragma unroll
  for (int mi = 0; mi < 8; ++mi)
#pragma unroll
    for (int ni = 0; ni < 4; ++ni)
#pragma unroll
      for (int j = 0; j < 4; ++j) part[mi][j] += fast_tanh(acc[mi][ni][j] + bl);
#pragma unroll
  for (int mi = 0; mi < 8; ++mi)
#pragma unroll
    for (int j = 0; j < 4; ++j) {
      float v = part[mi][j];
      v += __shfl_xor(v, 1, 64);
      v += __shfl_xor(v, 2, 64);
      v += __shfl_xor(v, 4, 64);
      v += __shfl_xor(v, 8, 64);
      part[mi][j] = v;
    }
  if ((lane & 15) == 0) {
    int slot = bc * 16 + tn * 4 + wc;
    int rg = (lane >> 4) * 4;
#pragma unroll
    for (int mi = 0; mi < 8; ++mi)
#pragma unroll
      for (int j = 0; j < 4; ++j) {
        int row = tm * 256 + wr * 128 + mi * 16 + rg + j;
        s_part[(size_t)slot * LL + row] = part[mi][j];
      }
  }
}

// ---------------------------------------------------------------------------
// K3: score_bar partials: sb = tanh(X_b @ w_v2[c] + b_v[c]), dot w_v1[c]
// grid: 256 blocks, XCD-chunked; sc_part [bc][8][1024], slot = tn*4+wc
// ---------------------------------------------------------------------------
__global__ __launch_bounds__(512, 2) void k_sbar(const u16* __restrict__ Xhi, const u16* __restrict__ Wv2T,
                                                 const float* __restrict__ b_v, const float* __restrict__ w_v1,
                                                 float* __restrict__ sc_part) {
  __shared__ u16 lA[3 * 256 * 32];
  __shared__ u16 lB[3 * 256 * 32];
  int lin = blockIdx.x;                       // 256
  int virt = (lin & 7) * 32 + (lin >> 3);
  int bc = virt >> 3, rem = virt & 7;
  int tm = rem >> 1, tn = rem & 1;
  int b = bc >> 2, c = bc & 3;
  const u16* Ahi = Xhi + (size_t)b * LL * DD + (size_t)tm * 256 * DD;
  const u16* Bhi = Wv2T + (size_t)c * DD * DD + (size_t)tn * 256 * DD;
  f32x4 acc[8][4];
#pragma unroll
  for (int mi = 0; mi < 8; ++mi)
#pragma unroll
    for (int ni = 0; ni < 4; ++ni) acc[mi][ni] = (f32x4){0.f, 0.f, 0.f, 0.f};
  gemm256<1, false>(Ahi, nullptr, Bhi, nullptr, lA, lB, acc);

  int lane = threadIdx.x & 63, wave = threadIdx.x >> 6;
  int wr = wave >> 2, wc = wave & 3;
  int cidx = lane & 15;
  float wv[4], bvv[4];
#pragma unroll
  for (int ni = 0; ni < 4; ++ni) {
    int col = tn * 256 + wc * 64 + ni * 16 + cidx;
    wv[ni] = w_v1[c * DD + col];
    bvv[ni] = b_v[c * DD + col];
  }
  float part[8][4];
#pragma unroll
  for (int mi = 0; mi < 8; ++mi)
#pragma unroll
    for (int j = 0; j < 4; ++j) part[mi][j] = 0.f;
#pragma unroll
  for (int mi = 0; mi < 8; ++mi)
#pragma unroll
    for (int ni = 0; ni < 4; ++ni)
#pragma unroll
      for (int j = 0; j < 4; ++j) part[mi][j] += fast_tanh(acc[mi][ni][j] + bvv[ni]) * wv[ni];
#pragma unroll
  for (int mi = 0; mi < 8; ++mi)
#pragma unroll
    for (int j = 0; j < 4; ++j) {
      float v = part[mi][j];
      v += __shfl_xor(v, 1, 64);
      v += __shfl_xor(v, 2, 64);
      v += __shfl_xor(v, 4, 64);
      v += __shfl_xor(v, 8, 64);
      part[mi][j] = v;
    }
  if ((lane & 15) == 0) {
    int slot = bc * 8 + tn * 4 + wc;
    int rg = (lane >> 4) * 4;
#pragma unroll
    for (int mi = 0; mi < 8; ++mi)
#pragma unroll
      for (int j = 0; j < 4; ++j) {
        int row = tm * 256 + wr * 128 + mi * 16 + rg + j;
        sc_part[(size_t)slot * LL + row] = part[mi][j];
      }
  }
}

// ---------------------------------------------------------------------------
// K4: softmaxes (a, a_bar) only.  grid(32), block(1024)
// ---------------------------------------------------------------------------
__device__ __forceinline__ float blk_max(float v, float* red, int tid) {
#pragma unroll
  for (int m = 32; m >= 1; m >>= 1) v = fmaxf(v, __shfl_xor(v, m, 64));
  if ((tid & 63) == 0) red[tid >> 6] = v;
  __syncthreads();
  float r = red[0];
#pragma unroll
  for (int k = 1; k < 16; ++k) r = fmaxf(r, red[k]);
  __syncthreads();
  return r;
}
__device__ __forceinline__ float blk_sum(float v, float* red, int tid) {
#pragma unroll
  for (int m = 32; m >= 1; m >>= 1) v += __shfl_xor(v, m, 64);
  if ((tid & 63) == 0) red[tid >> 6] = v;
  __syncthreads();
  float r = red[0];
#pragma unroll
  for (int k = 1; k < 16; ++k) r += red[k];
  __syncthreads();
  return r;
}

__global__ __launch_bounds__(1024) void k_softmax(const float* __restrict__ s_part,
                                                  const float* __restrict__ sc_part,
                                                  const float* __restrict__ pad_k,
                                                  float* __restrict__ a_out,
                                                  float* __restrict__ abar_out) {
  __shared__ float red[16];
  int bc = blockIdx.x, b = bc >> 2;
  int i = threadIdx.x;
  float pk = pad_k[b * LL + i];

  float s = pk;
#pragma unroll
  for (int p = 0; p < 16; ++p) s += s_part[(size_t)(bc * 16 + p) * LL + i];
  float mx = blk_max(s, red, i);
  float e = expf(s - mx);
  float sum = blk_sum(e, red, i);
  a_out[bc * LL + i] = e / sum;

  float sb = pk;
#pragma unroll
  for (int p = 0; p < 8; ++p) sb += sc_part[(size_t)(bc * 8 + p) * LL + i];
  float mx2 = blk_max(sb, red, i);
  float e2 = expf(sb - mx2);
  float sum2 = blk_sum(e2, red, i);
  abar_out[bc * LL + i] = e2 / sum2;
}

// ---------------------------------------------------------------------------
// K4b: pooled GEMV, wide: grid 256 = (bc, d-chunk of 64), block 256.
// pooled[bc,d] = sum_l abar[bc,l] * X[b,l,d].  Coalesced 256B row bursts.
// ---------------------------------------------------------------------------
__global__ __launch_bounds__(256) void k_pool(const float* __restrict__ abar,
                                              const float* __restrict__ X,
                                              float* __restrict__ pooled) {
  __shared__ float pp[256];
  int bc = blockIdx.x >> 3, dc = blockIdx.x & 7;
  int b = bc >> 2;
  int t = threadIdx.x;
  int d = dc * 64 + (t & 63);
  int lg = t >> 6;                          // 0..3
  const float* xb = X + (size_t)b * LL * DD + d;
  const float* ab = abar + (size_t)bc * LL;
  float s0 = 0.f, s1 = 0.f;
  for (int l = lg; l < LL; l += 8) {
    s0 += ab[l] * xb[(size_t)l * DD];
    s1 += ab[l + 4] * xb[(size_t)(l + 4) * DD];
  }
  pp[t] = s0 + s1;
  __syncthreads();
  if (t < 64)
    pooled[bc * DD + dc * 64 + t] = pp[t] + pp[t + 64] + pp[t + 128] + pp[t + 192];
}

// ---------------------------------------------------------------------------
// K5: assemble C_features (B,L,D,5), coalesced via LDS repack.  grid(16384),256
// ---------------------------------------------------------------------------
__global__ __launch_bounds__(256) void k_assemble(const float* __restrict__ X,
                                                  const float* __restrict__ pad_k,
                                                  const float* __restrict__ a,
                                                  const float* __restrict__ pooled,
                                                  float* __restrict__ out) {
  __shared__ float buf[1280];
  int t = threadIdx.x;
  size_t idx = (size_t)blockIdx.x * 256 + t;   // flat (b,l,d)
  int d = (int)(idx & (DD - 1));
  int bl = (int)(idx >> 9);                    // b*L + l
  int b = bl >> 10;
  int l = bl & (LL - 1);
  float x = X[idx];
  float pk2 = (pad_k[bl] + 99999.0f) * (1.0f / 99999.0f);
#pragma unroll
  for (int c = 0; c < 4; ++c) {
    float av = a[(size_t)(b * 4 + c) * LL + l];
    float pv = pooled[(size_t)(b * 4 + c) * DD + d];
    buf[t * 5 + c] = av * x + pv * pk2;
  }
  buf[t * 5 + 4] = x;
  __syncthreads();
  size_t base = (size_t)blockIdx.x * 1280;
#pragma unroll
  for (int k = 0; k < 5; ++k) out[base + k * 256 + t] = buf[k * 256 + t];
}

// ---------------------------------------------------------------------------
extern "C" void kernel_launch(void* const* d_in, const int* in_sizes, int n_in,
                              void* d_out, int out_size, void* d_ws, size_t ws_size,
                              hipStream_t stream) {
  (void)in_sizes; (void)n_in; (void)out_size;
  const float* X     = (const float*)d_in[0];
  const float* pad_k = (const float*)d_in[1];
  const float* w_l   = (const float*)d_in[2];
  const float* b_l   = (const float*)d_in[3];
  const float* w_v1  = (const float*)d_in[4];
  const float* w_v2  = (const float*)d_in[5];
  const float* b_v   = (const float*)d_in[6];
  float* out = (float*)d_out;

  // Workspace layout (bytes). Xlo falls back into d_out's tail gap if ws small.
  char* wsp = (char*)d_ws;
  const size_t NEED = 26279936;
  bool small_ws = ws_size < NEED;
  u16* Xhi = (u16*)wsp;                                               // 8,388,608 B
  u16* Xlo = small_ws ? (u16*)((char*)d_out + 67108864)
                      : (u16*)(wsp + 8388608);                        // 8,388,608 B
  size_t off = small_ws ? 8388608 : 16777216;
  u16* WlThi = (u16*)(wsp + off);  off += 2097152;
  u16* WlTlo = (u16*)(wsp + off);  off += 2097152;
  u16* Wv2T  = (u16*)(wsp + off);  off += 2097152;
  float* s_part  = (float*)(wsp + off); off += 2097152;   // [32][16][1024] f32
  float* sc_part = (float*)(wsp + off); off += 1048576;   // [32][8][1024] f32
  float* pooled  = (float*)(wsp + off); off += 65536;     // [32][512] f32

  // mat_l hi/lo staged in d_out scratch (consumed before final writes).
  u16* mhi = (u16*)d_out;
  u16* mlo = (u16*)d_out + 16777216;

  float* a_out    = out + 20971520;   // (B,C,L,1)
  float* abar_out = out + 21004288;   // (B,C,L,1)

  k_split<<<4096, 256, 0, stream>>>((const float4v*)X, Xhi, Xlo);
  k_tsplit<<<dim3(16, 16, 4), dim3(32, 8), 0, stream>>>(w_l, WlThi, WlTlo);
  k_tsplit<<<dim3(16, 16, 4), dim3(32, 8), 0, stream>>>(w_v2, Wv2T, nullptr);

  k_matl<<<256, 512, 0, stream>>>(Xhi, Xlo, WlThi, WlTlo, mhi, mlo);
  k_s<<<512, 512, 0, stream>>>(Xhi, Xlo, mhi, mlo, b_l, s_part);
  k_sbar<<<256, 512, 0, stream>>>(Xhi, Wv2T, b_v, w_v1, sc_part);

  k_softmax<<<32, 1024, 0, stream>>>(s_part, sc_part, pad_k, a_out, abar_out);
  k_pool<<<256, 256, 0, stream>>>(abar_out, X, pooled);
  k_assemble<<<16384, 256, 0, stream>>>(X, pad_k, a_out, pooled, out);
}

// Round 13
// 240.677 us; speedup vs baseline: 1.0830x; 1.0830x over previous
//
#include <hip/hip_runtime.h>

// Problem dims
#define BB 8
#define LL 1024
#define DD 512
#define CC 4

typedef unsigned short u16;
typedef unsigned int u32;
typedef __attribute__((ext_vector_type(8))) short bf16x8;
typedef __attribute__((ext_vector_type(4))) float f32x4;
typedef __attribute__((ext_vector_type(4))) unsigned short u16x4;
typedef __attribute__((ext_vector_type(4))) float float4v;

typedef __attribute__((address_space(1))) const u32 gu32;
typedef __attribute__((address_space(3))) u32 lu32;
typedef __attribute__((address_space(3))) u16 l16;

__device__ __forceinline__ void gload16(const void* g, void* l) {
  __builtin_amdgcn_global_load_lds((gu32*)g, (lu32*)l, 16, 0, 0);
}
__device__ __forceinline__ u32 lds_off(const u16* p) {   // LDS byte offset
  return (u32)(uintptr_t)(l16*)p;
}

__device__ __forceinline__ u16 f2bf(float f) {
  unsigned u = __float_as_uint(f);
  u += 0x7FFF + ((u >> 16) & 1);   // round-to-nearest-even
  return (u16)(u >> 16);
}
__device__ __forceinline__ float bf2f(u16 h) {
  return __uint_as_float(((unsigned)h) << 16);
}
// saturation-safe fast tanh: 1 - 2/(e^{2x}+1)
__device__ __forceinline__ float fast_tanh(float x) {
  return 1.0f - 2.0f / (__expf(2.0f * x) + 1.0f);
}

// ---------------------------------------------------------------------------
// K0a: split fp32 X -> bf16 hi + bf16 lo
// ---------------------------------------------------------------------------
__global__ __launch_bounds__(256) void k_split(const float4v* __restrict__ x,
                                               u16* __restrict__ hi, u16* __restrict__ lo) {
  int i = blockIdx.x * 256 + threadIdx.x;
  float4v v = x[i];
  u16x4 h, l;
#pragma unroll
  for (int k = 0; k < 4; ++k) {
    u16 hh = f2bf(v[k]);
    h[k] = hh;
    l[k] = f2bf(v[k] - bf2f(hh));
  }
  *(u16x4*)&hi[(size_t)i * 4] = h;
  *(u16x4*)&lo[(size_t)i * 4] = l;
}

// ---------------------------------------------------------------------------
// K0b: transpose (C,D,D) weight and split to bf16 hi (+ optional lo)
// ---------------------------------------------------------------------------
__global__ __launch_bounds__(256) void k_tsplit(const float* __restrict__ w,
                                                u16* __restrict__ thi, u16* __restrict__ tlo) {
  __shared__ float t[32][33];
  int c = blockIdx.z;
  int tx = threadIdx.x;        // 0..31
  int ty = threadIdx.y;        // 0..7
  int e0 = blockIdx.x * 32, d0 = blockIdx.y * 32;
#pragma unroll
  for (int k = 0; k < 32; k += 8)
    t[ty + k][tx] = w[((size_t)c * DD + d0 + ty + k) * DD + e0 + tx];
  __syncthreads();
#pragma unroll
  for (int k = 0; k < 32; k += 8) {
    float v = t[tx][ty + k];
    size_t o = ((size_t)c * DD + e0 + ty + k) * DD + d0 + tx;
    u16 h = f2bf(v);
    thi[o] = h;
    if (tlo) tlo[o] = f2bf(v - bf2f(h));
  }
}

// ---------------------------------------------------------------------------
// 256x256-tile GEMM mainloop: C = A(MxK) · B(NxK)^T, row-major stride 512.
// 512 threads = 8 waves (wr 0..1, wc 0..3); wave tile 128x64 = 8x4 frags.
// BK=32, TRIPLE-buffered LDS [3][256][32] u16 per operand = 96 KB total.
// 16B-slot swizzle slot^=(row>>1)&3, source-side + read-side (0 conflicts).
// R12-proven engine: staging issue SPREAD through the step:
//   iter t: STAGE_PAIR(t+2, half0) -> vmcnt(6) -> s_barrier ->
//           [ds_read/MFMA pipelined; STAGE_PAIR(t+2, half1) after cluster 2]
//           -> lgkm(0) -> s_barrier
// Ledger: at wait, outstanding = {t:4, t+1:4, t+2:2} = 10 -> vmcnt(6)
// retires exactly tile t's 4.  Peel waits 4 / 0 unchanged.
// SPLIT: 3 segments hi*hi + lo*hi + hi*lo (K-expanded 1536).
// ---------------------------------------------------------------------------
#define DSR(dst, addr, OFF) \
  asm volatile("ds_read_b128 %0, %1 offset:" #OFF : "=v"(dst) : "v"(addr))
#define LGKM(N) \
  do { __builtin_amdgcn_sched_barrier(0); \
       asm volatile("s_waitcnt lgkmcnt(" #N ")" ::: "memory"); \
       __builtin_amdgcn_sched_barrier(0); } while (0)

template<int NSEG, bool SPLIT>
__device__ __forceinline__ void gemm256(const u16* __restrict__ Ahi, const u16* __restrict__ Alo,
                                        const u16* __restrict__ Bhi, const u16* __restrict__ Blo,
                                        u16* lA, u16* lB, f32x4 (&acc)[8][4]) {
  const int tid = threadIdx.x;            // 0..511
  const int lane = tid & 63;
  const int wave = tid >> 6;              // 0..7
  const int wr = wave >> 2, wc = wave & 3;
  const int fr = lane & 15;
  const int fq = lane >> 4;               // quarter 0..3
  const int srow = tid >> 2;              // 0..127
  const int xs = (tid & 3) ^ ((srow >> 1) & 3);   // pre-swizzled source slot
  const size_t soff = (size_t)srow * DD + (size_t)xs * 8;
  const int sidx = fq ^ ((fr >> 1) & 3);
  const u32 ra = lds_off(lA) + (u32)((wr * 128 + fr) * 64 + sidx * 16);
  const u32 rb = lds_off(lB) + (u32)((wc * 64 + fr) * 64 + sidx * 16);

  const int NT = NSEG * 16;

  // one {A,B} pair for row-half `half` of tile t into buffer elem-offset beo
#define STAGE_PAIR(t, beo, half) do {                                         \
    const int seg_ = SPLIT ? ((t) >> 4) : 0;                                  \
    const int kp_ = ((t) & 15) * 32;                                          \
    const u16* As_ = (SPLIT && seg_ == 1) ? Alo : Ahi;                        \
    const u16* Bs_ = (SPLIT && seg_ == 2) ? Blo : Bhi;                        \
    gload16(As_ + soff + (size_t)(half) * 128 * DD + kp_,                     \
            lA + (beo) + tid * 8 + (half) * 4096);                            \
    gload16(Bs_ + soff + (size_t)(half) * 128 * DD + kp_,                     \
            lB + (beo) + tid * 8 + (half) * 4096);                            \
  } while (0)

#define MFMA2(m0, m1) do {                                                    \
    _Pragma("unroll")                                                         \
    for (int ni = 0; ni < 4; ++ni)                                            \
      acc[m0][ni] = __builtin_amdgcn_mfma_f32_16x16x32_bf16(                  \
          af[m0], bv[ni], acc[m0][ni], 0, 0, 0);                              \
    _Pragma("unroll")                                                         \
    for (int ni = 0; ni < 4; ++ni)                                            \
      acc[m1][ni] = __builtin_amdgcn_mfma_f32_16x16x32_bf16(                  \
          af[m1], bv[ni], acc[m1][ni], 0, 0, 0);                              \
  } while (0)

  // peel-version compute: no mid-issue
#define COMPUTE_PEEL(bo_) do {                                                \
    u32 aA_ = ra + (bo_), aB_ = rb + (bo_);                                   \
    bf16x8 af[8], bv[4];                                                      \
    DSR(bv[0], aB_, 0);    DSR(bv[1], aB_, 1024);                             \
    DSR(bv[2], aB_, 2048); DSR(bv[3], aB_, 3072);                             \
    DSR(af[0], aA_, 0);    DSR(af[1], aA_, 1024);                             \
    DSR(af[2], aA_, 2048); DSR(af[3], aA_, 3072);                             \
    LGKM(2);                                                                  \
    __builtin_amdgcn_s_setprio(1);                                            \
    MFMA2(0, 1);                                                              \
    DSR(af[4], aA_, 4096); DSR(af[5], aA_, 5120);                             \
    LGKM(2);                                                                  \
    MFMA2(2, 3);                                                              \
    DSR(af[6], aA_, 6144); DSR(af[7], aA_, 7168);                             \
    LGKM(2);                                                                  \
    MFMA2(4, 5);                                                              \
    LGKM(0);                                                                  \
    MFMA2(6, 7);                                                              \
    __builtin_amdgcn_s_setprio(0);                                            \
    __builtin_amdgcn_s_barrier();  /* reads retired: buf reusable */          \
  } while (0)

  STAGE_PAIR(0, 0, 0);      STAGE_PAIR(0, 0, 1);
  STAGE_PAIR(1, 8192, 0);   STAGE_PAIR(1, 8192, 1);
  int be = 16384;   // dest elems for stage t+2 at t=0 (buf 2)
  u32 bo = 0;       // read bytes for compute t at t=0 (buf 0)
#pragma unroll 1
  for (int t = 0; t < NT - 2; ++t) {
    STAGE_PAIR(t + 2, be, 0);
    __builtin_amdgcn_sched_barrier(0);
    asm volatile("s_waitcnt vmcnt(6)" ::: "memory");   // tile t landed
    __builtin_amdgcn_sched_barrier(0);
    __builtin_amdgcn_s_barrier();                      // data ready
    __builtin_amdgcn_sched_barrier(0);
    {
      u32 aA_ = ra + bo, aB_ = rb + bo;
      bf16x8 af[8], bv[4];
      DSR(bv[0], aB_, 0);    DSR(bv[1], aB_, 1024);
      DSR(bv[2], aB_, 2048); DSR(bv[3], aB_, 3072);
      DSR(af[0], aA_, 0);    DSR(af[1], aA_, 1024);
      DSR(af[2], aA_, 2048); DSR(af[3], aA_, 3072);
      LGKM(2);                    // bv0-3, af0-1 ready; af2-3 in flight
      __builtin_amdgcn_s_setprio(1);
      MFMA2(0, 1);
      DSR(af[4], aA_, 4096); DSR(af[5], aA_, 5120);
      LGKM(2);                    // af2-3 ready; af4-5 in flight
      MFMA2(2, 3);
      STAGE_PAIR(t + 2, be, 1);   // mid-step staging issue (fine interleave)
      DSR(af[6], aA_, 6144); DSR(af[7], aA_, 7168);
      LGKM(2);                    // af4-5 ready; af6-7 in flight
      MFMA2(4, 5);
      LGKM(0);                    // all reads retired
      MFMA2(6, 7);
      __builtin_amdgcn_s_setprio(0);
      __builtin_amdgcn_s_barrier();  // reads retired: buf reusable
    }
    be = (be == 16384) ? 0 : be + 8192;
    bo = (bo == 32768u) ? 0u : bo + 16384u;
  }
  // peel NT-2
  __builtin_amdgcn_sched_barrier(0);
  asm volatile("s_waitcnt vmcnt(4)" ::: "memory");
  __builtin_amdgcn_sched_barrier(0);
  __builtin_amdgcn_s_barrier();
  __builtin_amdgcn_sched_barrier(0);
  COMPUTE_PEEL(bo);
  bo = (bo == 32768u) ? 0u : bo + 16384u;
  // peel NT-1
  __builtin_amdgcn_sched_barrier(0);
  asm volatile("s_waitcnt vmcnt(0)" ::: "memory");
  __builtin_amdgcn_sched_barrier(0);
  __builtin_amdgcn_s_barrier();
  __builtin_amdgcn_sched_barrier(0);
  COMPUTE_PEEL(bo);
#undef STAGE_PAIR
#undef COMPUTE_PEEL
#undef MFMA2
}

// ---------------------------------------------------------------------------
// K1: mat_l[b,c] = X_b @ W_c  (split x split), epilogue splits result to bf16 hi/lo
// grid: 256 blocks (tm 0..3, tn 0..1 per bc), XCD-chunked decode
// ---------------------------------------------------------------------------
__global__ __launch_bounds__(512, 2) void k_matl(const u16* __restrict__ Xhi, const u16* __restrict__ Xlo,
                                                 const u16* __restrict__ Whi, const u16* __restrict__ Wlo,
                                                 u16* __restrict__ mhi, u16* __restrict__ mlo) {
  __shared__ u16 lA[3 * 256 * 32];
  __shared__ u16 lB[3 * 256 * 32];
  int lin = blockIdx.x;                       // 256
  int virt = (lin & 7) * 32 + (lin >> 3);     // XCD-chunked
  int bc = virt >> 3, rem = virt & 7;
  int tm = rem >> 1, tn = rem & 1;
  int b = bc >> 2, c = bc & 3;
  const u16* Ahi = Xhi + (size_t)b * LL * DD + (size_t)tm * 256 * DD;
  const u16* Alo = Xlo + (size_t)b * LL * DD + (size_t)tm * 256 * DD;
  const u16* Bhi = Whi + (size_t)c * DD * DD + (size_t)tn * 256 * DD;
  const u16* Blo = Wlo + (size_t)c * DD * DD + (size_t)tn * 256 * DD;
  f32x4 acc[8][4];
#pragma unroll
  for (int mi = 0; mi < 8; ++mi)
#pragma unroll
    for (int ni = 0; ni < 4; ++ni) acc[mi][ni] = (f32x4){0.f, 0.f, 0.f, 0.f};
  gemm256<3, true>(Ahi, Alo, Bhi, Blo, lA, lB, acc);

  int lane = threadIdx.x & 63, wave = threadIdx.x >> 6;
  int wr = wave >> 2, wc = wave & 3;
  int rgrp = (lane >> 4) * 4, cidx = lane & 15;
#pragma unroll
  for (int mi = 0; mi < 8; ++mi)
#pragma unroll
    for (int ni = 0; ni < 4; ++ni) {
      int row = tm * 256 + wr * 128 + mi * 16 + rgrp;
      int col = tn * 256 + wc * 64 + ni * 16 + cidx;
#pragma unroll
      for (int j = 0; j < 4; ++j) {
        float v = acc[mi][ni][j];
        size_t o = ((size_t)bc * LL + row + j) * DD + col;
        u16 h = f2bf(v);
        mhi[o] = h;
        mlo[o] = f2bf(v - bf2f(h));
      }
    }
}

// ---------------------------------------------------------------------------
// K2: s partials: per 256x256 tile of M = X_b @ mat_l[b,c]^T, tanh + row-sum
// grid: 512 blocks, XCD-chunked; s_part [bc][16][1024], slot = tn*4+wc
// ---------------------------------------------------------------------------
__global__ __launch_bounds__(512, 2) void k_s(const u16* __restrict__ Xhi, const u16* __restrict__ Xlo,
                                              const u16* __restrict__ mhi, const u16* __restrict__ mlo,
                                              const float* __restrict__ b_l, float* __restrict__ s_part) {
  __shared__ u16 lA[3 * 256 * 32];
  __shared__ u16 lB[3 * 256 * 32];
  int lin = blockIdx.x;                       // 512
  int virt = (lin & 7) * 64 + (lin >> 3);     // XCD-chunked
  int bc = virt >> 4, rem = virt & 15;
  int tm = rem >> 2, tn = rem & 3;
  int b = bc >> 2, c = bc & 3;
  const u16* Ahi = Xhi + (size_t)b * LL * DD + (size_t)tm * 256 * DD;
  const u16* Alo = Xlo + (size_t)b * LL * DD + (size_t)tm * 256 * DD;
  const u16* Bhi = mhi + (size_t)bc * LL * DD + (size_t)tn * 256 * DD;
  const u16* Blo = mlo + (size_t)bc * LL * DD + (size_t)tn * 256 * DD;
  f32x4 acc[8][4];
#pragma unroll
  for (int mi = 0; mi < 8; ++mi)
#pragma unroll
    for (int ni = 0; ni < 4; ++ni) acc[mi][ni] = (f32x4){0.f, 0.f, 0.f, 0.f};
  gemm256<3, true>(Ahi, Alo, Bhi, Blo, lA, lB, acc);

  int lane = threadIdx.x & 63, wave = threadIdx.x >> 6;
  int wr = wave >> 2, wc = wave & 3;
  float bl = b_l[c];
  float part[8][4];
#pragma unroll
  for (int mi = 0; mi < 8; ++mi)
#pragma unroll
    for (int j = 0; j < 4; ++j) part[mi][j] = 0.f;
#pragma unroll
  for (int mi = 0; mi < 8; ++mi)
#pragma unroll
    for (int ni = 0; ni < 4; ++ni)
#pragma unroll
      for (int j = 0; j < 4; ++j) part[mi][j] += fast_tanh(acc[mi][ni][j] + bl);
#pragma unroll
  for (int mi = 0; mi < 8; ++mi)
#pragma unroll
    for (int j = 0; j < 4; ++j) {
      float v = part[mi][j];
      v += __shfl_xor(v, 1, 64);
      v += __shfl_xor(v, 2, 64);
      v += __shfl_xor(v, 4, 64);
      v += __shfl_xor(v, 8, 64);
      part[mi][j] = v;
    }
  if ((lane & 15) == 0) {
    int slot = bc * 16 + tn * 4 + wc;
    int rg = (lane >> 4) * 4;
#pragma unroll
    for (int mi = 0; mi < 8; ++mi)
#pragma unroll
      for (int j = 0; j < 4; ++j) {
        int row = tm * 256 + wr * 128 + mi * 16 + rg + j;
        s_part[(size_t)slot * LL + row] = part[mi][j];
      }
  }
}

// ---------------------------------------------------------------------------
// K3: score_bar partials: sb = tanh(X_b @ w_v2[c] + b_v[c]), dot w_v1[c]
// grid: 256 blocks, XCD-chunked; sc_part [bc][8][1024], slot = tn*4+wc
// ---------------------------------------------------------------------------
__global__ __launch_bounds__(512, 2) void k_sbar(const u16* __restrict__ Xhi, const u16* __restrict__ Wv2T,
                                                 const float* __restrict__ b_v, const float* __restrict__ w_v1,
                                                 float* __restrict__ sc_part) {
  __shared__ u16 lA[3 * 256 * 32];
  __shared__ u16 lB[3 * 256 * 32];
  int lin = blockIdx.x;                       // 256
  int virt = (lin & 7) * 32 + (lin >> 3);
  int bc = virt >> 3, rem = virt & 7;
  int tm = rem >> 1, tn = rem & 1;
  int b = bc >> 2, c = bc & 3;
  const u16* Ahi = Xhi + (size_t)b * LL * DD + (size_t)tm * 256 * DD;
  const u16* Bhi = Wv2T + (size_t)c * DD * DD + (size_t)tn * 256 * DD;
  f32x4 acc[8][4];
#pragma unroll
  for (int mi = 0; mi < 8; ++mi)
#pragma unroll
    for (int ni = 0; ni < 4; ++ni) acc[mi][ni] = (f32x4){0.f, 0.f, 0.f, 0.f};
  gemm256<1, false>(Ahi, nullptr, Bhi, nullptr, lA, lB, acc);

  int lane = threadIdx.x & 63, wave = threadIdx.x >> 6;
  int wr = wave >> 2, wc = wave & 3;
  int cidx = lane & 15;
  float wv[4], bvv[4];
#pragma unroll
  for (int ni = 0; ni < 4; ++ni) {
    int col = tn * 256 + wc * 64 + ni * 16 + cidx;
    wv[ni] = w_v1[c * DD + col];
    bvv[ni] = b_v[c * DD + col];
  }
  float part[8][4];
#pragma unroll
  for (int mi = 0; mi < 8; ++mi)
#pragma unroll
    for (int j = 0; j < 4; ++j) part[mi][j] = 0.f;
#pragma unroll
  for (int mi = 0; mi < 8; ++mi)
#pragma unroll
    for (int ni = 0; ni < 4; ++ni)
#pragma unroll
      for (int j = 0; j < 4; ++j) part[mi][j] += fast_tanh(acc[mi][ni][j] + bvv[ni]) * wv[ni];
#pragma unroll
  for (int mi = 0; mi < 8; ++mi)
#pragma unroll
    for (int j = 0; j < 4; ++j) {
      float v = part[mi][j];
      v += __shfl_xor(v, 1, 64);
      v += __shfl_xor(v, 2, 64);
      v += __shfl_xor(v, 4, 64);
      v += __shfl_xor(v, 8, 64);
      part[mi][j] = v;
    }
  if ((lane & 15) == 0) {
    int slot = bc * 8 + tn * 4 + wc;
    int rg = (lane >> 4) * 4;
#pragma unroll
    for (int mi = 0; mi < 8; ++mi)
#pragma unroll
      for (int j = 0; j < 4; ++j) {
        int row = tm * 256 + wr * 128 + mi * 16 + rg + j;
        sc_part[(size_t)slot * LL + row] = part[mi][j];
      }
  }
}

// ---------------------------------------------------------------------------
// K4: softmaxes (a, a_bar) + pooled GEMV (integrated — R11 epilogue,
// measured-good; R12's split k_pool regressed ~25us).  grid(32), block(1024)
// ---------------------------------------------------------------------------
__device__ __forceinline__ float blk_max(float v, float* red, int tid) {
#pragma unroll
  for (int m = 32; m >= 1; m >>= 1) v = fmaxf(v, __shfl_xor(v, m, 64));
  if ((tid & 63) == 0) red[tid >> 6] = v;
  __syncthreads();
  float r = red[0];
#pragma unroll
  for (int k = 1; k < 16; ++k) r = fmaxf(r, red[k]);
  __syncthreads();
  return r;
}
__device__ __forceinline__ float blk_sum(float v, float* red, int tid) {
#pragma unroll
  for (int m = 32; m >= 1; m >>= 1) v += __shfl_xor(v, m, 64);
  if ((tid & 63) == 0) red[tid >> 6] = v;
  __syncthreads();
  float r = red[0];
#pragma unroll
  for (int k = 1; k < 16; ++k) r += red[k];
  __syncthreads();
  return r;
}

__global__ __launch_bounds__(1024) void k_softmax(const float* __restrict__ s_part,
                                                  const float* __restrict__ sc_part,
                                                  const float* __restrict__ pad_k,
                                                  const float* __restrict__ X,
                                                  float* __restrict__ a_out,
                                                  float* __restrict__ abar_out,
                                                  float* __restrict__ pooled) {
  __shared__ float red[16];
  __shared__ float sm_abar[LL];
  __shared__ float pp[DD];
  int bc = blockIdx.x, b = bc >> 2;
  int i = threadIdx.x;
  float pk = pad_k[b * LL + i];

  float s = pk;
#pragma unroll
  for (int p = 0; p < 16; ++p) s += s_part[(size_t)(bc * 16 + p) * LL + i];
  float mx = blk_max(s, red, i);
  float e = expf(s - mx);
  float sum = blk_sum(e, red, i);
  float a = e / sum;
  a_out[bc * LL + i] = a;

  float sb = pk;
#pragma unroll
  for (int p = 0; p < 8; ++p) sb += sc_part[(size_t)(bc * 8 + p) * LL + i];
  float mx2 = blk_max(sb, red, i);
  float e2 = expf(sb - mx2);
  float sum2 = blk_sum(e2, red, i);
  float ab = e2 / sum2;
  abar_out[bc * LL + i] = ab;
  sm_abar[i] = ab;
  __syncthreads();

  // pooled GEMV over all 1024 threads: thread (h,d) sums half the L range
  {
    int d = i & (DD - 1), h = i >> 9;            // h in {0,1}
    const float* xb = X + (size_t)b * LL * DD + (size_t)h * 512 * DD + d;
    const float* abp = sm_abar + h * 512;
    float a0 = 0.f, a1 = 0.f, a2 = 0.f, a3 = 0.f;
    for (int l = 0; l < 512; l += 4) {
      a0 += abp[l + 0] * xb[(size_t)(l + 0) * DD];
      a1 += abp[l + 1] * xb[(size_t)(l + 1) * DD];
      a2 += abp[l + 2] * xb[(size_t)(l + 2) * DD];
      a3 += abp[l + 3] * xb[(size_t)(l + 3) * DD];
    }
    float sv = (a0 + a1) + (a2 + a3);
    if (h == 1) pp[d] = sv;
    __syncthreads();
    if (h == 0) pooled[bc * DD + d] = sv + pp[d];
  }
}

// ---------------------------------------------------------------------------
// K5: assemble C_features (B,L,D,5), coalesced via LDS repack.  grid(16384),256
// ---------------------------------------------------------------------------
__global__ __launch_bounds__(256) void k_assemble(const float* __restrict__ X,
                                                  const float* __restrict__ pad_k,
                                                  const float* __restrict__ a,
                                                  const float* __restrict__ pooled,
                                                  float* __restrict__ out) {
  __shared__ float buf[1280];
  int t = threadIdx.x;
  size_t idx = (size_t)blockIdx.x * 256 + t;   // flat (b,l,d)
  int d = (int)(idx & (DD - 1));
  int bl = (int)(idx >> 9);                    // b*L + l
  int b = bl >> 10;
  int l = bl & (LL - 1);
  float x = X[idx];
  float pk2 = (pad_k[bl] + 99999.0f) * (1.0f / 99999.0f);
#pragma unroll
  for (int c = 0; c < 4; ++c) {
    float av = a[(size_t)(b * 4 + c) * LL + l];
    float pv = pooled[(size_t)(b * 4 + c) * DD + d];
    buf[t * 5 + c] = av * x + pv * pk2;
  }
  buf[t * 5 + 4] = x;
  __syncthreads();
  size_t base = (size_t)blockIdx.x * 1280;
#pragma unroll
  for (int k = 0; k < 5; ++k) out[base + k * 256 + t] = buf[k * 256 + t];
}

// ---------------------------------------------------------------------------
extern "C" void kernel_launch(void* const* d_in, const int* in_sizes, int n_in,
                              void* d_out, int out_size, void* d_ws, size_t ws_size,
                              hipStream_t stream) {
  (void)in_sizes; (void)n_in; (void)out_size;
  const float* X     = (const float*)d_in[0];
  const float* pad_k = (const float*)d_in[1];
  const float* w_l   = (const float*)d_in[2];
  const float* b_l   = (const float*)d_in[3];
  const float* w_v1  = (const float*)d_in[4];
  const float* w_v2  = (const float*)d_in[5];
  const float* b_v   = (const float*)d_in[6];
  float* out = (float*)d_out;

  // Workspace layout (bytes). Xlo falls back into d_out's tail gap if ws small.
  char* wsp = (char*)d_ws;
  const size_t NEED = 26279936;
  bool small_ws = ws_size < NEED;
  u16* Xhi = (u16*)wsp;                                               // 8,388,608 B
  u16* Xlo = small_ws ? (u16*)((char*)d_out + 67108864)
                      : (u16*)(wsp + 8388608);                        // 8,388,608 B
  size_t off = small_ws ? 8388608 : 16777216;
  u16* WlThi = (u16*)(wsp + off);  off += 2097152;
  u16* WlTlo = (u16*)(wsp + off);  off += 2097152;
  u16* Wv2T  = (u16*)(wsp + off);  off += 2097152;
  float* s_part  = (float*)(wsp + off); off += 2097152;   // [32][16][1024] f32
  float* sc_part = (float*)(wsp + off); off += 1048576;   // [32][8][1024] f32
  float* pooled  = (float*)(wsp + off); off += 65536;     // [32][512] f32

  // mat_l hi/lo staged in d_out scratch (consumed before final writes).
  u16* mhi = (u16*)d_out;
  u16* mlo = (u16*)d_out + 16777216;

  float* a_out    = out + 20971520;   // (B,C,L,1)
  float* abar_out = out + 21004288;   // (B,C,L,1)

  k_split<<<4096, 256, 0, stream>>>((const float4v*)X, Xhi, Xlo);
  k_tsplit<<<dim3(16, 16, 4), dim3(32, 8), 0, stream>>>(w_l, WlThi, WlTlo);
  k_tsplit<<<dim3(16, 16, 4), dim3(32, 8), 0, stream>>>(w_v2, Wv2T, nullptr);

  k_matl<<<256, 512, 0, stream>>>(Xhi, Xlo, WlThi, WlTlo, mhi, mlo);
  k_s<<<512, 512, 0, stream>>>(Xhi, Xlo, mhi, mlo, b_l, s_part);
  k_sbar<<<256, 512, 0, stream>>>(Xhi, Wv2T, b_v, w_v1, sc_part);

  k_softmax<<<32, 1024, 0, stream>>>(s_part, sc_part, pad_k, X, a_out, abar_out, pooled);
  k_assemble<<<16384, 256, 0, stream>>>(X, pad_k, a_out, pooled, out);
}

// Round 14
// 226.705 us; speedup vs baseline: 1.1498x; 1.0616x over previous
//
#include <hip/hip_runtime.h>

// Problem dims
#define BB 8
#define LL 1024
#define DD 512
#define CC 4

typedef unsigned short u16;
typedef unsigned int u32;
typedef __attribute__((ext_vector_type(8))) short bf16x8;
typedef __attribute__((ext_vector_type(4))) float f32x4;
typedef __attribute__((ext_vector_type(4))) unsigned short u16x4;
typedef __attribute__((ext_vector_type(4))) float float4v;

typedef __attribute__((address_space(1))) const u32 gu32;
typedef __attribute__((address_space(3))) u32 lu32;
typedef __attribute__((address_space(3))) u16 l16;

__device__ __forceinline__ void gload16(const void* g, void* l) {
  __builtin_amdgcn_global_load_lds((gu32*)g, (lu32*)l, 16, 0, 0);
}
__device__ __forceinline__ u32 lds_off(const u16* p) {   // LDS byte offset
  return (u32)(uintptr_t)(l16*)p;
}

__device__ __forceinline__ u16 f2bf(float f) {
  unsigned u = __float_as_uint(f);
  u += 0x7FFF + ((u >> 16) & 1);   // round-to-nearest-even
  return (u16)(u >> 16);
}
__device__ __forceinline__ float bf2f(u16 h) {
  return __uint_as_float(((unsigned)h) << 16);
}
// saturation-safe fast tanh: 1 - 2/(e^{2x}+1)
__device__ __forceinline__ float fast_tanh(float x) {
  return 1.0f - 2.0f / (__expf(2.0f * x) + 1.0f);
}

// ---------------------------------------------------------------------------
// K0a: split fp32 X -> bf16 hi + bf16 lo
// ---------------------------------------------------------------------------
__global__ __launch_bounds__(256) void k_split(const float4v* __restrict__ x,
                                               u16* __restrict__ hi, u16* __restrict__ lo) {
  int i = blockIdx.x * 256 + threadIdx.x;
  float4v v = x[i];
  u16x4 h, l;
#pragma unroll
  for (int k = 0; k < 4; ++k) {
    u16 hh = f2bf(v[k]);
    h[k] = hh;
    l[k] = f2bf(v[k] - bf2f(hh));
  }
  *(u16x4*)&hi[(size_t)i * 4] = h;
  *(u16x4*)&lo[(size_t)i * 4] = l;
}

// ---------------------------------------------------------------------------
// K0b: transpose (C,D,D) weight and split to bf16 hi (+ optional lo)
// ---------------------------------------------------------------------------
__global__ __launch_bounds__(256) void k_tsplit(const float* __restrict__ w,
                                                u16* __restrict__ thi, u16* __restrict__ tlo) {
  __shared__ float t[32][33];
  int c = blockIdx.z;
  int tx = threadIdx.x;        // 0..31
  int ty = threadIdx.y;        // 0..7
  int e0 = blockIdx.x * 32, d0 = blockIdx.y * 32;
#pragma unroll
  for (int k = 0; k < 32; k += 8)
    t[ty + k][tx] = w[((size_t)c * DD + d0 + ty + k) * DD + e0 + tx];
  __syncthreads();
#pragma unroll
  for (int k = 0; k < 32; k += 8) {
    float v = t[tx][ty + k];
    size_t o = ((size_t)c * DD + e0 + ty + k) * DD + d0 + tx;
    u16 h = f2bf(v);
    thi[o] = h;
    if (tlo) tlo[o] = f2bf(v - bf2f(h));
  }
}

// ---------------------------------------------------------------------------
// 256x256-tile GEMM mainloop, BK=64: C = A(MxK)·B(NxK)^T, row-major stride 512.
// 512 threads = 8 waves (wr 0..1, wc 0..3); wave tile 128x64 = 8x4 frags,
// 64 MFMA per wave per step (2 kk-halves of 32).
// DOUBLE-buffered LDS [2][256][64] u16 per operand = 128 KB total (1 blk/CU,
// same residency as R13's 96 KB).  Half the barriers of the BK=32 engine.
// Swizzle (both-sides, rule 21): phys_slot = logical ^ (row&7); linear DMA
// dest + inverse-swizzled SOURCE (xs = (tid&7)^((tid>>3)&7)); reads use
// p0 = fq^(fr&7), kk=1 via dk = ((p0^4)-p0)*16.
// vmcnt ledger: TOP stages 4 loads, MID 4 (inside compute).  Steady-state
// wait vmcnt(4) retires exactly tile t's 8; peel vmcnt(0).  Buffer reuse
// guarded by trailing lgkmcnt(0)+s_barrier of each COMPUTE.
// SPLIT: 3 segments hi*hi + lo*hi + hi*lo (K-expanded 1536).
// ---------------------------------------------------------------------------
#define DSR(dst, addr, OFF) \
  asm volatile("ds_read_b128 %0, %1 offset:" #OFF : "=v"(dst) : "v"(addr))
#define LGKM(N) \
  do { __builtin_amdgcn_sched_barrier(0); \
       asm volatile("s_waitcnt lgkmcnt(" #N ")" ::: "memory"); \
       __builtin_amdgcn_sched_barrier(0); } while (0)

template<int NSEG, bool SPLIT>
__device__ __forceinline__ void gemm256(const u16* __restrict__ Ahi, const u16* __restrict__ Alo,
                                        const u16* __restrict__ Bhi, const u16* __restrict__ Blo,
                                        u16* lA, u16* lB, f32x4 (&acc)[8][4]) {
  const int tid = threadIdx.x;            // 0..511
  const int lane = tid & 63;
  const int wave = tid >> 6;              // 0..7
  const int wr = wave >> 2, wc = wave & 3;
  const int fr = lane & 15;
  const int fq = lane >> 4;               // quarter 0..3
  // staging: issue i covers rows i*64 + (tid>>3); phys slot tid&7 (8 per row)
  const int xs = (tid & 7) ^ ((tid >> 3) & 7);      // inverse-swizzled source slot
  const size_t soff = (size_t)(tid >> 3) * DD + (size_t)xs * 8;
  // read addressing
  const int p0 = fq ^ (fr & 7);                     // phys slot for kk=0
  const int dk = ((p0 ^ 4) - p0) * 16;              // byte delta to kk=1 slot
  const u32 ra = lds_off(lA) + (u32)((wr * 128 + fr) * 128 + p0 * 16);
  const u32 rb = lds_off(lB) + (u32)((wc * 64 + fr) * 128 + p0 * 16);

  const int NT = NSEG * 8;

#define STAGE_TOP(T, beo) do {                                                \
    const int seg_ = SPLIT ? ((T) >> 3) : 0;                                  \
    const int kp_ = ((T) & 7) * 64;                                           \
    const u16* As_ = (SPLIT && seg_ == 1) ? Alo : Ahi;                        \
    const u16* Bs_ = (SPLIT && seg_ == 2) ? Blo : Bhi;                        \
    gload16(As_ + soff + kp_,                 lA + (beo) + tid * 8);          \
    gload16(Bs_ + soff + kp_,                 lB + (beo) + tid * 8);          \
    gload16(As_ + soff + (size_t)64 * DD + kp_, lA + (beo) + tid * 8 + 4096); \
    gload16(Bs_ + soff + (size_t)64 * DD + kp_, lB + (beo) + tid * 8 + 4096); \
  } while (0)

#define STAGE_MID(T, beo) do {                                                \
    const int seg_ = SPLIT ? ((T) >> 3) : 0;                                  \
    const int kp_ = ((T) & 7) * 64;                                           \
    const u16* As_ = (SPLIT && seg_ == 1) ? Alo : Ahi;                        \
    const u16* Bs_ = (SPLIT && seg_ == 2) ? Blo : Bhi;                        \
    gload16(As_ + soff + (size_t)128 * DD + kp_, lA + (beo) + tid * 8 + 8192);  \
    gload16(Bs_ + soff + (size_t)128 * DD + kp_, lB + (beo) + tid * 8 + 8192);  \
    gload16(As_ + soff + (size_t)192 * DD + kp_, lA + (beo) + tid * 8 + 12288); \
    gload16(Bs_ + soff + (size_t)192 * DD + kp_, lB + (beo) + tid * 8 + 12288); \
  } while (0)

#define MFMA2(m0, m1) do {                                                    \
    _Pragma("unroll")                                                         \
    for (int ni = 0; ni < 4; ++ni)                                            \
      acc[m0][ni] = __builtin_amdgcn_mfma_f32_16x16x32_bf16(                  \
          af[m0], bv[ni], acc[m0][ni], 0, 0, 0);                              \
    _Pragma("unroll")                                                         \
    for (int ni = 0; ni < 4; ++ni)                                            \
      acc[m1][ni] = __builtin_amdgcn_mfma_f32_16x16x32_bf16(                  \
          af[m1], bv[ni], acc[m1][ni], 0, 0, 0);                              \
  } while (0)

  // one kk-half: 12 ds_reads pipelined against 32 MFMA (R12-proven pattern)
#define HALF(aA_, aB_) do {                                                   \
    bf16x8 af[8], bv[4];                                                      \
    DSR(bv[0], aB_, 0);    DSR(bv[1], aB_, 2048);                             \
    DSR(bv[2], aB_, 4096); DSR(bv[3], aB_, 6144);                             \
    DSR(af[0], aA_, 0);    DSR(af[1], aA_, 2048);                             \
    DSR(af[2], aA_, 4096); DSR(af[3], aA_, 6144);                             \
    LGKM(2);                                                                  \
    MFMA2(0, 1);                                                              \
    DSR(af[4], aA_, 8192); DSR(af[5], aA_, 10240);                            \
    LGKM(2);                                                                  \
    MFMA2(2, 3);                                                              \
    DSR(af[6], aA_, 12288); DSR(af[7], aA_, 14336);                           \
    LGKM(2);                                                                  \
    MFMA2(4, 5);                                                              \
    LGKM(0);                                                                  \
    MFMA2(6, 7);                                                              \
  } while (0)

  // same but with the mid-step staging spliced after cluster 2
#define HALF_MID(aA_, aB_, T, beo) do {                                       \
    bf16x8 af[8], bv[4];                                                      \
    DSR(bv[0], aB_, 0);    DSR(bv[1], aB_, 2048);                             \
    DSR(bv[2], aB_, 4096); DSR(bv[3], aB_, 6144);                             \
    DSR(af[0], aA_, 0);    DSR(af[1], aA_, 2048);                             \
    DSR(af[2], aA_, 4096); DSR(af[3], aA_, 6144);                             \
    LGKM(2);                                                                  \
    MFMA2(0, 1);                                                              \
    DSR(af[4], aA_, 8192); DSR(af[5], aA_, 10240);                            \
    LGKM(2);                                                                  \
    MFMA2(2, 3);                                                              \
    STAGE_MID(T, beo);                                                        \
    DSR(af[6], aA_, 12288); DSR(af[7], aA_, 14336);                           \
    LGKM(2);                                                                  \
    MFMA2(4, 5);                                                              \
    LGKM(0);                                                                  \
    MFMA2(6, 7);                                                              \
  } while (0)

  STAGE_TOP(0, 0);
  STAGE_MID(0, 0);
  int beN = 16384;  // dest elems for tile t+1 (buf 1 at t=0)
  u32 bo = 0;       // read bytes for tile t (buf 0 at t=0)
#pragma unroll 1
  for (int t = 0; t < NT - 1; ++t) {
    STAGE_TOP(t + 1, beN);
    __builtin_amdgcn_sched_barrier(0);
    asm volatile("s_waitcnt vmcnt(4)" ::: "memory");   // tile t fully landed
    __builtin_amdgcn_sched_barrier(0);
    __builtin_amdgcn_s_barrier();                      // data ready
    __builtin_amdgcn_sched_barrier(0);
    {
      u32 aA0 = ra + bo, aB0 = rb + bo;
      __builtin_amdgcn_s_setprio(1);
      HALF_MID(aA0, aB0, t + 1, beN);                  // kk=0 + mid staging
      u32 aA1 = aA0 + dk, aB1 = aB0 + dk;
      HALF(aA1, aB1);                                  // kk=1
      __builtin_amdgcn_s_setprio(0);
      __builtin_amdgcn_s_barrier();                    // reads retired: buf reusable
    }
    beN ^= 16384;
    bo ^= 32768u;
  }
  // peel: last tile
  __builtin_amdgcn_sched_barrier(0);
  asm volatile("s_waitcnt vmcnt(0)" ::: "memory");
  __builtin_amdgcn_sched_barrier(0);
  __builtin_amdgcn_s_barrier();
  __builtin_amdgcn_sched_barrier(0);
  {
    u32 aA0 = ra + bo, aB0 = rb + bo;
    __builtin_amdgcn_s_setprio(1);
    HALF(aA0, aB0);
    u32 aA1 = aA0 + dk, aB1 = aB0 + dk;
    HALF(aA1, aB1);
    __builtin_amdgcn_s_setprio(0);
  }
#undef STAGE_TOP
#undef STAGE_MID
#undef HALF
#undef HALF_MID
#undef MFMA2
}

// ---------------------------------------------------------------------------
// K1: mat_l[b,c] = X_b @ W_c  (split x split), epilogue splits result to bf16 hi/lo
// grid: 256 blocks (tm 0..3, tn 0..1 per bc), XCD-chunked decode
// ---------------------------------------------------------------------------
__global__ __launch_bounds__(512, 2) void k_matl(const u16* __restrict__ Xhi, const u16* __restrict__ Xlo,
                                                 const u16* __restrict__ Whi, const u16* __restrict__ Wlo,
                                                 u16* __restrict__ mhi, u16* __restrict__ mlo) {
  __shared__ u16 lA[2 * 256 * 64];
  __shared__ u16 lB[2 * 256 * 64];
  int lin = blockIdx.x;                       // 256
  int virt = (lin & 7) * 32 + (lin >> 3);     // XCD-chunked
  int bc = virt >> 3, rem = virt & 7;
  int tm = rem >> 1, tn = rem & 1;
  int b = bc >> 2, c = bc & 3;
  const u16* Ahi = Xhi + (size_t)b * LL * DD + (size_t)tm * 256 * DD;
  const u16* Alo = Xlo + (size_t)b * LL * DD + (size_t)tm * 256 * DD;
  const u16* Bhi = Whi + (size_t)c * DD * DD + (size_t)tn * 256 * DD;
  const u16* Blo = Wlo + (size_t)c * DD * DD + (size_t)tn * 256 * DD;
  f32x4 acc[8][4];
#pragma unroll
  for (int mi = 0; mi < 8; ++mi)
#pragma unroll
    for (int ni = 0; ni < 4; ++ni) acc[mi][ni] = (f32x4){0.f, 0.f, 0.f, 0.f};
  gemm256<3, true>(Ahi, Alo, Bhi, Blo, lA, lB, acc);

  int lane = threadIdx.x & 63, wave = threadIdx.x >> 6;
  int wr = wave >> 2, wc = wave & 3;
  int rgrp = (lane >> 4) * 4, cidx = lane & 15;
#pragma unroll
  for (int mi = 0; mi < 8; ++mi)
#pragma unroll
    for (int ni = 0; ni < 4; ++ni) {
      int row = tm * 256 + wr * 128 + mi * 16 + rgrp;
      int col = tn * 256 + wc * 64 + ni * 16 + cidx;
#pragma unroll
      for (int j = 0; j < 4; ++j) {
        float v = acc[mi][ni][j];
        size_t o = ((size_t)bc * LL + row + j) * DD + col;
        u16 h = f2bf(v);
        mhi[o] = h;
        mlo[o] = f2bf(v - bf2f(h));
      }
    }
}

// ---------------------------------------------------------------------------
// K2: s partials: per 256x256 tile of M = X_b @ mat_l[b,c]^T, tanh + row-sum
// grid: 512 blocks, XCD-chunked; s_part [bc][16][1024], slot = tn*4+wc
// ---------------------------------------------------------------------------
__global__ __launch_bounds__(512, 2) void k_s(const u16* __restrict__ Xhi, const u16* __restrict__ Xlo,
                                              const u16* __restrict__ mhi, const u16* __restrict__ mlo,
                                              const float* __restrict__ b_l, float* __restrict__ s_part) {
  __shared__ u16 lA[2 * 256 * 64];
  __shared__ u16 lB[2 * 256 * 64];
  int lin = blockIdx.x;                       // 512
  int virt = (lin & 7) * 64 + (lin >> 3);     // XCD-chunked
  int bc = virt >> 4, rem = virt & 15;
  int tm = rem >> 2, tn = rem & 3;
  int b = bc >> 2, c = bc & 3;
  const u16* Ahi = Xhi + (size_t)b * LL * DD + (size_t)tm * 256 * DD;
  const u16* Alo = Xlo + (size_t)b * LL * DD + (size_t)tm * 256 * DD;
  const u16* Bhi = mhi + (size_t)bc * LL * DD + (size_t)tn * 256 * DD;
  const u16* Blo = mlo + (size_t)bc * LL * DD + (size_t)tn * 256 * DD;
  f32x4 acc[8][4];
#pragma unroll
  for (int mi = 0; mi < 8; ++mi)
#pragma unroll
    for (int ni = 0; ni < 4; ++ni) acc[mi][ni] = (f32x4){0.f, 0.f, 0.f, 0.f};
  gemm256<3, true>(Ahi, Alo, Bhi, Blo, lA, lB, acc);

  int lane = threadIdx.x & 63, wave = threadIdx.x >> 6;
  int wr = wave >> 2, wc = wave & 3;
  float bl = b_l[c];
  float part[8][4];
#pragma unroll
  for (int mi = 0; mi < 8; ++mi)
#pragma unroll
    for (int j = 0; j < 4; ++j) part[mi][j] = 0.f;
#pragma unroll
  for (int mi = 0; mi < 8; ++mi)
#pragma unroll
    for (int ni = 0; ni < 4; ++ni)
#pragma unroll
      for (int j = 0; j < 4; ++j) part[mi][j] += fast_tanh(acc[mi][ni][j] + bl);
#pragma unroll
  for (int mi = 0; mi < 8; ++mi)
#pragma unroll
    for (int j = 0; j < 4; ++j) {
      float v = part[mi][j];
      v += __shfl_xor(v, 1, 64);
      v += __shfl_xor(v, 2, 64);
      v += __shfl_xor(v, 4, 64);
      v += __shfl_xor(v, 8, 64);
      part[mi][j] = v;
    }
  if ((lane & 15) == 0) {
    int slot = bc * 16 + tn * 4 + wc;
    int rg = (lane >> 4) * 4;
#pragma unroll
    for (int mi = 0; mi < 8; ++mi)
#pragma unroll
      for (int j = 0; j < 4; ++j) {
        int row = tm * 256 + wr * 128 + mi * 16 + rg + j;
        s_part[(size_t)slot * LL + row] = part[mi][j];
      }
  }
}

// ---------------------------------------------------------------------------
// K3: score_bar partials: sb = tanh(X_b @ w_v2[c] + b_v[c]), dot w_v1[c]
// grid: 256 blocks, XCD-chunked; sc_part [bc][8][1024], slot = tn*4+wc
// ---------------------------------------------------------------------------
__global__ __launch_bounds__(512, 2) void k_sbar(const u16* __restrict__ Xhi, const u16* __restrict__ Wv2T,
                                                 const float* __restrict__ b_v, const float* __restrict__ w_v1,
                                                 float* __restrict__ sc_part) {
  __shared__ u16 lA[2 * 256 * 64];
  __shared__ u16 lB[2 * 256 * 64];
  int lin = blockIdx.x;                       // 256
  int virt = (lin & 7) * 32 + (lin >> 3);
  int bc = virt >> 3, rem = virt & 7;
  int tm = rem >> 1, tn = rem & 1;
  int b = bc >> 2, c = bc & 3;
  const u16* Ahi = Xhi + (size_t)b * LL * DD + (size_t)tm * 256 * DD;
  const u16* Bhi = Wv2T + (size_t)c * DD * DD + (size_t)tn * 256 * DD;
  f32x4 acc[8][4];
#pragma unroll
  for (int mi = 0; mi < 8; ++mi)
#pragma unroll
    for (int ni = 0; ni < 4; ++ni) acc[mi][ni] = (f32x4){0.f, 0.f, 0.f, 0.f};
  gemm256<1, false>(Ahi, nullptr, Bhi, nullptr, lA, lB, acc);

  int lane = threadIdx.x & 63, wave = threadIdx.x >> 6;
  int wr = wave >> 2, wc = wave & 3;
  int cidx = lane & 15;
  float wv[4], bvv[4];
#pragma unroll
  for (int ni = 0; ni < 4; ++ni) {
    int col = tn * 256 + wc * 64 + ni * 16 + cidx;
    wv[ni] = w_v1[c * DD + col];
    bvv[ni] = b_v[c * DD + col];
  }
  float part[8][4];
#pragma unroll
  for (int mi = 0; mi < 8; ++mi)
#pragma unroll
    for (int j = 0; j < 4; ++j) part[mi][j] = 0.f;
#pragma unroll
  for (int mi = 0; mi < 8; ++mi)
#pragma unroll
    for (int ni = 0; ni < 4; ++ni)
#pragma unroll
      for (int j = 0; j < 4; ++j) part[mi][j] += fast_tanh(acc[mi][ni][j] + bvv[ni]) * wv[ni];
#pragma unroll
  for (int mi = 0; mi < 8; ++mi)
#pragma unroll
    for (int j = 0; j < 4; ++j) {
      float v = part[mi][j];
      v += __shfl_xor(v, 1, 64);
      v += __shfl_xor(v, 2, 64);
      v += __shfl_xor(v, 4, 64);
      v += __shfl_xor(v, 8, 64);
      part[mi][j] = v;
    }
  if ((lane & 15) == 0) {
    int slot = bc * 8 + tn * 4 + wc;
    int rg = (lane >> 4) * 4;
#pragma unroll
    for (int mi = 0; mi < 8; ++mi)
#pragma unroll
      for (int j = 0; j < 4; ++j) {
        int row = tm * 256 + wr * 128 + mi * 16 + rg + j;
        sc_part[(size_t)slot * LL + row] = part[mi][j];
      }
  }
}

// ---------------------------------------------------------------------------
// K4: softmaxes (a, a_bar) + pooled GEMV (integrated, measured-good).
// grid(32), block(1024)
// ---------------------------------------------------------------------------
__device__ __forceinline__ float blk_max(float v, float* red, int tid) {
#pragma unroll
  for (int m = 32; m >= 1; m >>= 1) v = fmaxf(v, __shfl_xor(v, m, 64));
  if ((tid & 63) == 0) red[tid >> 6] = v;
  __syncthreads();
  float r = red[0];
#pragma unroll
  for (int k = 1; k < 16; ++k) r = fmaxf(r, red[k]);
  __syncthreads();
  return r;
}
__device__ __forceinline__ float blk_sum(float v, float* red, int tid) {
#pragma unroll
  for (int m = 32; m >= 1; m >>= 1) v += __shfl_xor(v, m, 64);
  if ((tid & 63) == 0) red[tid >> 6] = v;
  __syncthreads();
  float r = red[0];
#pragma unroll
  for (int k = 1; k < 16; ++k) r += red[k];
  __syncthreads();
  return r;
}

__global__ __launch_bounds__(1024) void k_softmax(const float* __restrict__ s_part,
                                                  const float* __restrict__ sc_part,
                                                  const float* __restrict__ pad_k,
                                                  const float* __restrict__ X,
                                                  float* __restrict__ a_out,
                                                  float* __restrict__ abar_out,
                                                  float* __restrict__ pooled) {
  __shared__ float red[16];
  __shared__ float sm_abar[LL];
  __shared__ float pp[DD];
  int bc = blockIdx.x, b = bc >> 2;
  int i = threadIdx.x;
  float pk = pad_k[b * LL + i];

  float s = pk;
#pragma unroll
  for (int p = 0; p < 16; ++p) s += s_part[(size_t)(bc * 16 + p) * LL + i];
  float mx = blk_max(s, red, i);
  float e = expf(s - mx);
  float sum = blk_sum(e, red, i);
  float a = e / sum;
  a_out[bc * LL + i] = a;

  float sb = pk;
#pragma unroll
  for (int p = 0; p < 8; ++p) sb += sc_part[(size_t)(bc * 8 + p) * LL + i];
  float mx2 = blk_max(sb, red, i);
  float e2 = expf(sb - mx2);
  float sum2 = blk_sum(e2, red, i);
  float ab = e2 / sum2;
  abar_out[bc * LL + i] = ab;
  sm_abar[i] = ab;
  __syncthreads();

  // pooled GEMV over all 1024 threads: thread (h,d) sums half the L range
  {
    int d = i & (DD - 1), h = i >> 9;            // h in {0,1}
    const float* xb = X + (size_t)b * LL * DD + (size_t)h * 512 * DD + d;
    const float* abp = sm_abar + h * 512;
    float a0 = 0.f, a1 = 0.f, a2 = 0.f, a3 = 0.f;
    for (int l = 0; l < 512; l += 4) {
      a0 += abp[l + 0] * xb[(size_t)(l + 0) * DD];
      a1 += abp[l + 1] * xb[(size_t)(l + 1) * DD];
      a2 += abp[l + 2] * xb[(size_t)(l + 2) * DD];
      a3 += abp[l + 3] * xb[(size_t)(l + 3) * DD];
    }
    float sv = (a0 + a1) + (a2 + a3);
    if (h == 1) pp[d] = sv;
    __syncthreads();
    if (h == 0) pooled[bc * DD + d] = sv + pp[d];
  }
}

// ---------------------------------------------------------------------------
// K5: assemble C_features (B,L,D,5), coalesced via LDS repack.  grid(16384),256
// ---------------------------------------------------------------------------
__global__ __launch_bounds__(256) void k_assemble(const float* __restrict__ X,
                                                  const float* __restrict__ pad_k,
                                                  const float* __restrict__ a,
                                                  const float* __restrict__ pooled,
                                                  float* __restrict__ out) {
  __shared__ float buf[1280];
  int t = threadIdx.x;
  size_t idx = (size_t)blockIdx.x * 256 + t;   // flat (b,l,d)
  int d = (int)(idx & (DD - 1));
  int bl = (int)(idx >> 9);                    // b*L + l
  int b = bl >> 10;
  int l = bl & (LL - 1);
  float x = X[idx];
  float pk2 = (pad_k[bl] + 99999.0f) * (1.0f / 99999.0f);
#pragma unroll
  for (int c = 0; c < 4; ++c) {
    float av = a[(size_t)(b * 4 + c) * LL + l];
    float pv = pooled[(size_t)(b * 4 + c) * DD + d];
    buf[t * 5 + c] = av * x + pv * pk2;
  }
  buf[t * 5 + 4] = x;
  __syncthreads();
  size_t base = (size_t)blockIdx.x * 1280;
#pragma unroll
  for (int k = 0; k < 5; ++k) out[base + k * 256 + t] = buf[k * 256 + t];
}

// ---------------------------------------------------------------------------
extern "C" void kernel_launch(void* const* d_in, const int* in_sizes, int n_in,
                              void* d_out, int out_size, void* d_ws, size_t ws_size,
                              hipStream_t stream) {
  (void)in_sizes; (void)n_in; (void)out_size;
  const float* X     = (const float*)d_in[0];
  const float* pad_k = (const float*)d_in[1];
  const float* w_l   = (const float*)d_in[2];
  const float* b_l   = (const float*)d_in[3];
  const float* w_v1  = (const float*)d_in[4];
  const float* w_v2  = (const float*)d_in[5];
  const float* b_v   = (const float*)d_in[6];
  float* out = (float*)d_out;

  // Workspace layout (bytes). Xlo falls back into d_out's tail gap if ws small.
  char* wsp = (char*)d_ws;
  const size_t NEED = 26279936;
  bool small_ws = ws_size < NEED;
  u16* Xhi = (u16*)wsp;                                               // 8,388,608 B
  u16* Xlo = small_ws ? (u16*)((char*)d_out + 67108864)
                      : (u16*)(wsp + 8388608);                        // 8,388,608 B
  size_t off = small_ws ? 8388608 : 16777216;
  u16* WlThi = (u16*)(wsp + off);  off += 2097152;
  u16* WlTlo = (u16*)(wsp + off);  off += 2097152;
  u16* Wv2T  = (u16*)(wsp + off);  off += 2097152;
  float* s_part  = (float*)(wsp + off); off += 2097152;   // [32][16][1024] f32
  float* sc_part = (float*)(wsp + off); off += 1048576;   // [32][8][1024] f32
  float* pooled  = (float*)(wsp + off); off += 65536;     // [32][512] f32

  // mat_l hi/lo staged in d_out scratch (consumed before final writes).
  u16* mhi = (u16*)d_out;
  u16* mlo = (u16*)d_out + 16777216;

  float* a_out    = out + 20971520;   // (B,C,L,1)
  float* abar_out = out + 21004288;   // (B,C,L,1)

  k_split<<<4096, 256, 0, stream>>>((const float4v*)X, Xhi, Xlo);
  k_tsplit<<<dim3(16, 16, 4), dim3(32, 8), 0, stream>>>(w_l, WlThi, WlTlo);
  k_tsplit<<<dim3(16, 16, 4), dim3(32, 8), 0, stream>>>(w_v2, Wv2T, nullptr);

  k_matl<<<256, 512, 0, stream>>>(Xhi, Xlo, WlThi, WlTlo, mhi, mlo);
  k_s<<<512, 512, 0, stream>>>(Xhi, Xlo, mhi, mlo, b_l, s_part);
  k_sbar<<<256, 512, 0, stream>>>(Xhi, Wv2T, b_v, w_v1, sc_part);

  k_softmax<<<32, 1024, 0, stream>>>(s_part, sc_part, pad_k, X, a_out, abar_out, pooled);
  k_assemble<<<16384, 256, 0, stream>>>(X, pad_k, a_out, pooled, out);
}